// Round 1
// baseline (215.945 us; speedup 1.0000x reference)
//
#include <hip/hip_runtime.h>
#include <hip/hip_cooperative_groups.h>
#include <math.h>

namespace cg = cooperative_groups;

#define BB 8
#define CC 1024
#define HH 56
#define WW 56
#define NB 256
#define NCLS 30
#define BC (BB * CC)             // 8192 planes
#define PLANE (HH * WW)          // 3136
#define NWORD (NB / 2)           // 128 packed u16-pairs per cell
#define CELLW (PLANE * NWORD)    // 401408 packed words, whole image
#define SLICES 16
#define PL_PER_SLICE (BC / SLICES)  // 512 planes

// ---------------------------------------------------------------------------
// Workspace layout (FULL mode, fits under the old 28.94 MB bound):
//   ps      @ 0         25,690,112 B   (fallback per-slice packed hists)
//   colhist @ 0            28,672 B   (ALIASES ps head: colhist is dead before
//   ghist   @ 28,672        1,024 B    the fallback overwrites ps — safe)
//   hist    @ 25,690,112 3,211,264 B   (fallback unpacked/integral hists)
//   meta    @ 28,901,376      256 B   (region int[3] @+0, flag u32 @+16)
//   pooled  @ 28,901,632   32,768 B
//   total = 28,934,400 B  (< previous needA = 28,938,240 -> ws definitely fits)
// ---------------------------------------------------------------------------
#define FULL_NEED 28934400ull
#define FAST_NEED 63488ull

// ---------------------------------------------------------------------------
// Kernel 0: zero the atomically-accumulated fast-path stats (7424 u32).
// ---------------------------------------------------------------------------
__global__ void zero_kernel(unsigned* __restrict__ p) {
    const int i = blockIdx.x * 256 + threadIdx.x;  // grid 29*256 = 7424 exact
    p[i] = 0u;
}

// ---------------------------------------------------------------------------
// Kernel 1: single streaming pass over x.
//  - global 256-bin histogram (u32 in LDS, atomic flush to ghist)
//  - row-0 per-column histograms (u16-packed in LDS, atomic flush to colhist)
// Block b owns planes [16b, 16b+16) -> fully contiguous, coalesced float4.
// 512 blocks x 256 thr = 2 blocks/CU, 8 waves/CU; LDS 29.7 KB -> fits 2/CU.
// Packing safety: per-block per-(w,bin) col count <= 16; global <= 8192 < 2^16.
// ---------------------------------------------------------------------------
__global__ __launch_bounds__(256) void ghist_kernel(const float* __restrict__ x,
                                                    unsigned* __restrict__ colhist,
                                                    unsigned* __restrict__ ghist) {
    __shared__ unsigned ch[HH * NWORD];  // 7168 packed words (28 KB)
    __shared__ unsigned gh[NB];
    const int tid = threadIdx.x;
    for (int i = tid; i < HH * NWORD; i += 256) ch[i] = 0u;
    gh[tid] = 0u;  // 256 threads == NB
    __syncthreads();

    const float4* __restrict__ xb =
        (const float4*)(x + (size_t)blockIdx.x * (16 * PLANE));
    for (int it = 0; it < 49; ++it) {      // 16*3136/4 = 12544 = 49*256
        const int j = it * 256 + tid;
        const float4 v = xb[j];
        const int e0 = j * 4;
        const int pl = e0 / PLANE;          // const-div -> magic mul
        const int li = e0 - pl * PLANE;     // plane-local idx, multiple of 4
        const bool r0 = (li < WW);          // this float4 lies in row 0
        const float vv[4] = {v.x, v.y, v.z, v.w};
#pragma unroll
        for (int e = 0; e < 4; ++e) {
            const float f = vv[e];
            if (f >= 0.f && f <= 1.f) {     // histc: OOR dropped
                int bin = (int)(f * 256.f); // floor (f>=0)
                if (bin > 255) bin = 255;   // v==1 -> last bin
                atomicAdd(&gh[bin], 1u);
                if (r0)
                    atomicAdd(&ch[(li + e) * NWORD + (bin >> 1)],
                              1u << ((bin & 1) << 4));
            }
        }
    }
    __syncthreads();
    for (int i = tid; i < HH * NWORD; i += 256) {
        const unsigned v = ch[i];
        if (v) atomicAdd(&colhist[i], v);   // sparse: ~900 nonzero/block
    }
    { const unsigned v = gh[tid]; if (v) atomicAdd(&ghist[tid], v); }
}

// ---------------------------------------------------------------------------
// Wave / entropy helpers (identical reduction order to the proven kernel).
// ---------------------------------------------------------------------------
__device__ __forceinline__ float wave_sum(float v) {
#pragma unroll
    for (int off = 32; off > 0; off >>= 1) v += __shfl_xor(v, off);
    return v;
}

__device__ __forceinline__ float ilook(const unsigned* __restrict__ integ,
                                       int a, int b, int bin) {
    return (a == 0 || b == 0)
               ? 0.f
               : (float)integ[((size_t)((a - 1) * WW + (b - 1))) * NB + bin];
}

__device__ float region_ent(const unsigned* __restrict__ integ, int lane,
                            int xd, int ys, int yd) {
    float hb[4];
    float hs = 0.f;
#pragma unroll
    for (int k = 0; k < 4; k++) {
        const int bin = lane + 64 * k;
        const float hv = ilook(integ, xd, yd, bin) - ilook(integ, xd, ys, bin);
        hb[k] = hv;
        hs += hv;
    }
    hs = wave_sum(hs);
    float e = 0.f;
#pragma unroll
    for (int k = 0; k < 4; k++) {
        const float p = hb[k] / hs;
        e += p * log2f(p + 1e-9f);
    }
    return -wave_sum(e);
}

// ---------------------------------------------------------------------------
// Kernel 2: fast decide. ent_y from colhist, argmax -> ys0, total_ent from
// ghist, Ts0 = ent_y[ys0]/total_ent (single-cell region entropy == column
// entropy: same integer counts). flag=1 -> done; flag=2 -> fallback continues.
// ---------------------------------------------------------------------------
__global__ __launch_bounds__(1024) void decide_fast_kernel(
    const unsigned* __restrict__ colhist, const unsigned* __restrict__ ghist,
    int* __restrict__ region, unsigned* __restrict__ flag) {
    __shared__ float ent_s[WW];
    const int tid = threadIdx.x;
    const int lane = tid & 63;
    const int wv = tid >> 6;

    for (int w = wv; w < WW; w += 16) {
        float hb[4], hs = 0.f;
#pragma unroll
        for (int k = 0; k < 4; k++) {
            const int bin = lane + 64 * k;
            const unsigned wd = colhist[w * NWORD + (bin >> 1)];
            hb[k] = (float)((wd >> ((bin & 1) << 4)) & 0xffffu);
            hs += hb[k];
        }
        hs = wave_sum(hs);
        float e = 0.f;
#pragma unroll
        for (int k = 0; k < 4; k++) {
            const float p = hb[k] / hs;
            e += p * log2f(p + 1e-9f);
        }
        e = -wave_sum(e);
        if (lane == 0) ent_s[w] = e;
    }
    __syncthreads();
    if (wv != 0) return;

    float best = -3.0e38f;
    int bestw = 0;
    for (int w = 0; w < WW; ++w) {
        const float e = ent_s[w];
        if (e > best) { best = e; bestw = w; }  // strict > keeps FIRST max
    }

    // total entropy from the global histogram
    float hb[4], hs = 0.f;
#pragma unroll
    for (int k = 0; k < 4; k++) {
        const int bin = lane + 64 * k;
        hb[k] = (float)ghist[bin];
        hs += hb[k];
    }
    hs = wave_sum(hs);
    float e = 0.f;
#pragma unroll
    for (int k = 0; k < 4; k++) {
        const float p = hb[k] / hs;
        e += p * log2f(p + 1e-9f);
    }
    const float total_ent = -wave_sum(e);

    const float Ts0 = best / total_ent;  // best == ent_s[bestw]
    if (lane == 0) {
        region[0] = 1;          // xd
        region[1] = bestw;      // ys
        region[2] = bestw + 1;  // yd
        *flag = (Ts0 >= 0.9f) ? 1u : 2u;
    }
}

// ---------------------------------------------------------------------------
// Kernel 3: cooperative fallback — full integral-histogram pipeline, only if
// the greedy loop actually needs to iterate (flag==2). Fast path: every block
// reads flag and returns (~2 us no-op dispatch).
// 256 blocks x 256 thr, LDS 28 KB -> all co-resident (1 block/CU min).
// ---------------------------------------------------------------------------
__global__ __launch_bounds__(256) void fallback_kernel(
    const float* __restrict__ x, unsigned* __restrict__ ps,
    unsigned* __restrict__ hist, int* __restrict__ region,
    const unsigned* __restrict__ flag) {
    if (*flag == 1u) return;  // all blocks exit together; no sync reached
    cg::grid_group grid = cg::this_grid();
    __shared__ unsigned lh[HH * NWORD];  // 7168 words, u16-packed
    const int tid = threadIdx.x;
    const int gtid = blockIdx.x * 256 + tid;

    // phase 1: per-(h,slice) tile histograms -> ps (non-atomic, tile-owned)
    for (int t = blockIdx.x; t < HH * SLICES; t += 256) {
        const int h = t % HH;
        const int slice = t / HH;
        for (int i = tid; i < HH * NWORD; i += 256) lh[i] = 0u;
        __syncthreads();
        const float* __restrict__ xb =
            x + (size_t)(slice * PL_PER_SLICE) * PLANE + h * WW;
        for (int it = 0; it < 28; ++it) {  // 512 planes * 14 float4 / 256
            const int j = it * 256 + tid;
            const int bcl = j / 14;
            const int wq = j - bcl * 14;
            const float4 v = *(const float4*)(xb + (size_t)bcl * PLANE + wq * 4);
            const float vv[4] = {v.x, v.y, v.z, v.w};
#pragma unroll
            for (int e = 0; e < 4; ++e) {
                const float f = vv[e];
                if (f >= 0.f && f <= 1.f) {
                    int bin = (int)(f * 256.f);
                    if (bin > 255) bin = 255;
                    atomicAdd(&lh[(wq * 4 + e) * NWORD + (bin >> 1)],
                              1u << ((bin & 1) << 4));
                }
            }
        }
        __syncthreads();
        unsigned* g = ps + (size_t)slice * CELLW + (size_t)h * WW * NWORD;
        for (int i = tid; i < HH * NWORD; i += 256) g[i] = lh[i];
        __syncthreads();
    }
    grid.sync();

    // phase 2: reduce 16 slices + unpack -> hist u32 [h][w][256]
    for (int idx = gtid; idx < CELLW; idx += 256 * 256) {
        unsigned s = 0;
#pragma unroll
        for (int sl = 0; sl < SLICES; ++sl) s += ps[(size_t)sl * CELLW + idx];
        ((uint2*)hist)[idx] = make_uint2(s & 0xffffu, s >> 16);
    }
    grid.sync();

    // phase 3: inclusive prefix along w (register-staged)
    if (gtid < HH * NB) {
        const int h = gtid >> 8, b = gtid & 255;
        unsigned* base = hist + (size_t)h * WW * NB + b;
        unsigned v[WW];
#pragma unroll
        for (int w = 0; w < WW; ++w) v[w] = base[(size_t)w * NB];
        unsigned c = 0;
#pragma unroll
        for (int w = 0; w < WW; ++w) { c += v[w]; base[(size_t)w * NB] = c; }
    }
    grid.sync();

    // phase 4: inclusive prefix along h
    if (gtid < WW * NB) {
        const int w = gtid >> 8, b = gtid & 255;
        unsigned* base = hist + (size_t)w * NB + b;
        unsigned v[HH];
#pragma unroll
        for (int h = 0; h < HH; ++h) v[h] = base[(size_t)h * WW * NB];
        unsigned c = 0;
#pragma unroll
        for (int h = 0; h < HH; ++h) { c += v[h]; base[(size_t)h * WW * NB] = c; }
    }
    grid.sync();

    // phase 5: greedy loop, block 0 wave 0, starting from fast-path region
    if (blockIdx.x == 0 && tid < 64) {
        const int lane = tid;
        const float total_ent = region_ent(hist, lane, HH, 0, WW);
        int xd = region[0], ys = region[1], yd = region[2];
        float Ts = region_ent(hist, lane, xd, ys, yd) / total_ent;
        bool done = false;
        int iter = 0;
        while (Ts < 0.9f && !done && iter < 1000) {
            iter++;
            const float e_cur = region_ent(hist, lane, xd, ys, yd);
            const int ysm = (ys - 1 < 0) ? 0 : ys - 1;
            const int ydp = (yd + 1 > WW) ? WW : yd + 1;
            const bool c1 = (xd + 1 < HH) &&
                            (region_ent(hist, lane, xd + 1, ys, yd) > e_cur);
            const bool c2 = !c1 && (ys - 1 >= 0) &&
                            (region_ent(hist, lane, xd, ysm, yd) > e_cur);
            const bool c3 = !c1 && !c2 && (yd + 1 < WW) &&
                            (region_ent(hist, lane, xd, ys, ydp) > e_cur);
            if (c1) xd = xd + 1;
            else if (c2) ys = ys - 1;
            else if (c3) yd = yd + 1;
            done = !(c1 || c2 || c3);
            Ts = region_ent(hist, lane, xd, ys, yd) / total_ent;
        }
        if (lane == 0) {
            region[0] = xd;
            region[1] = ys;
            region[2] = yd;
        }
    }
}

// ---------------------------------------------------------------------------
// Kernel 4: masked mean-pool. 32 blocks x 256. Small regions (the fast path,
// n==1): thread-per-plane, one load each, massively parallel. Large regions:
// wave-per-plane with lane striding.
// ---------------------------------------------------------------------------
__global__ __launch_bounds__(256) void pool_kernel(const float* __restrict__ x,
                                                   const int* __restrict__ region,
                                                   float* __restrict__ pooled) {
    const int xd = region[0], ys = region[1], yd = region[2];
    const int Wd = yd - ys;
    const int n = xd * Wd;
    const float area = fmaxf((float)n, 1.f);
    if (n <= 16) {
        const int bc = blockIdx.x * 256 + threadIdx.x;  // grid 32*256 == BC
        const float* plane = x + (size_t)bc * PLANE;
        float s = 0.f;
        for (int j = 0; j < n; ++j) {
            const int r = j / Wd;
            const int cc = ys + (j - r * Wd);
            s += plane[r * WW + cc];
        }
        pooled[bc] = s / area;
    } else {
        const int wid = (blockIdx.x * 256 + threadIdx.x) >> 6;  // 128 waves
        const int lane = threadIdx.x & 63;
        for (int bc = wid; bc < BC; bc += 128) {
            const float* plane = x + (size_t)bc * PLANE;
            float s = 0.f;
            for (int j = lane; j < n; j += 64) {
                const int r = j / Wd;
                const int cc = ys + (j - r * Wd);
                s += plane[r * WW + cc];
            }
#pragma unroll
            for (int off = 32; off > 0; off >>= 1) s += __shfl_xor(s, off);
            if (lane == 0) pooled[bc] = s / area;
        }
    }
}

// ---------------------------------------------------------------------------
// Kernel 5: FC. Unchanged from the verified kernel (absmax == 0).
// ---------------------------------------------------------------------------
__global__ __launch_bounds__(256) void fc_kernel(const float* __restrict__ pooled,
                                                 const float* __restrict__ wfc,
                                                 float* __restrict__ out) {
    __shared__ float red[240];
    const int b = blockIdx.x;
    const int t = threadIdx.x;
    if (t < 240) {
        const int chunk = t / NCLS;
        const int n = t - chunk * NCLS;
        const float* pv = pooled + b * CC + chunk * 128;
        const float* wv = wfc + (size_t)(chunk * 128) * NCLS + n;
        float a0 = 0.f, a1 = 0.f, a2 = 0.f, a3 = 0.f;
        for (int c = 0; c < 128; c += 4) {
            a0 += pv[c + 0] * wv[(c + 0) * NCLS];
            a1 += pv[c + 1] * wv[(c + 1) * NCLS];
            a2 += pv[c + 2] * wv[(c + 2) * NCLS];
            a3 += pv[c + 3] * wv[(c + 3) * NCLS];
        }
        red[t] = (a0 + a1) + (a2 + a3);
    }
    __syncthreads();
    if (t < NCLS) {
        float s = 0.f;
#pragma unroll
        for (int ch = 0; ch < 8; ++ch) s += red[ch * NCLS + t];
        out[b * NCLS + t] = s;
    }
}

// ---------------------------------------------------------------------------
extern "C" void kernel_launch(void* const* d_in, const int* in_sizes, int n_in,
                              void* d_out, int out_size, void* d_ws, size_t ws_size,
                              hipStream_t stream) {
    const float* x = (const float*)d_in[0];    // [8,1024,56,56]
    const float* wfc = (const float*)d_in[1];  // [1024,30]
    float* out = (float*)d_out;                // [8,30]

    unsigned char* ws = (unsigned char*)d_ws;
    const bool full = (ws_size >= FULL_NEED);

    // fast-path stats alias the head of the fallback's ps buffer (dead by the
    // time fallback overwrites it)
    unsigned* colhist = (unsigned*)ws;                   // 28,672 B
    unsigned* ghist = (unsigned*)(ws + HH * NWORD * 4);  // 1,024 B
    unsigned* ps = (unsigned*)ws;                        // 25,690,112 B (fallback)
    unsigned* hist = (unsigned*)(ws + (size_t)SLICES * CELLW * 4);  // 3,211,264 B
    int* region;
    unsigned* flag;
    float* pooled;
    if (full) {
        unsigned char* meta = ws + 28901376ull;
        region = (int*)meta;
        flag = (unsigned*)(meta + 16);
        pooled = (float*)(ws + 28901632ull);
    } else {  // tiny-ws fallback: fast path only
        region = (int*)(ws + 29696);
        flag = (unsigned*)(ws + 29696 + 16);
        pooled = (float*)(ws + 30720);
    }

    zero_kernel<<<29, 256, 0, stream>>>(colhist);  // colhist+ghist contiguous
    ghist_kernel<<<512, 256, 0, stream>>>(x, colhist, ghist);
    decide_fast_kernel<<<1, 1024, 0, stream>>>(colhist, ghist, region, flag);
    if (full) {
        const float* xx = x;
        unsigned* psp = ps;
        unsigned* hp = hist;
        int* rp = region;
        unsigned* fp = flag;
        void* kargs[] = {(void*)&xx, (void*)&psp, (void*)&hp, (void*)&rp,
                         (void*)&fp};
        hipLaunchCooperativeKernel((const void*)fallback_kernel, dim3(256),
                                   dim3(256), kargs, 0, stream);
    }
    pool_kernel<<<32, 256, 0, stream>>>(x, region, pooled);
    fc_kernel<<<BB, 256, 0, stream>>>(pooled, wfc, out);
}

// Round 2
// 202.769 us; speedup vs baseline: 1.0650x; 1.0650x over previous
//
#include <hip/hip_runtime.h>
#include <hip/hip_cooperative_groups.h>
#include <math.h>

namespace cg = cooperative_groups;

#define BB 8
#define CC 1024
#define HH 56
#define WW 56
#define NB 256
#define NCLS 30
#define BC (BB * CC)             // 8192 planes
#define PLANE (HH * WW)          // 3136
#define NWORD (NB / 2)           // 128 packed u16-pairs per cell
#define CELLW (PLANE * NWORD)    // 401408 packed words, whole image
#define SLICES 16
#define PL_PER_SLICE (BC / SLICES)  // 512 planes

#define NPART 16                 // partial global hists (atomic-contention split)
#define GH_BLOCKS 3136           // 6,422,528 float4 / 2048 per block
#define F4_PER_BLOCK 2048        // 8 float4 per thread, register-prefetched

// ---------------------------------------------------------------------------
// Workspace layout (FULL mode, unchanged total):
//   ps      @ 0          25,690,112 B  (fallback per-slice packed hists)
//   colhist @ 0              28,672 B  (ALIASES ps head: dead before fallback)
//   gpart   @ 28,672         16,384 B  (16 partial 256-bin global hists)
//   hist    @ 25,690,112  3,211,264 B
//   meta    @ 28,901,376       256 B  (region int[3] @+0, flag u32 @+16)
//   pooled  @ 28,901,632    32,768 B
// ---------------------------------------------------------------------------
#define FULL_NEED 28934400ull

// ---------------------------------------------------------------------------
// Kernel 0: zero colhist + gpart (7168 + 4096 = 11264 u32, contiguous).
// ---------------------------------------------------------------------------
__global__ void zero_kernel(unsigned* __restrict__ p) {
    p[blockIdx.x * 256 + threadIdx.x] = 0u;  // grid 44*256 = 11264 exact
}

// ---------------------------------------------------------------------------
// Kernel 1: pure global 256-bin histogram.
//  grid 3136 x 256: ~8 blocks/CU resident (4 KB LDS, 44-ish VGPR) -> ~32 waves.
//  Per-wave privatized LDS hist (4 copies) -> intra-wave contention only.
//  All 8 float4 loads issued before any use -> 8 outstanding loads/thread.
//  Flush: per-bin sum of 4 copies -> atomicAdd into gpart[blockIdx&15] so
//  same-address global chains are 3136/16 = 196 deep instead of 3136.
// ---------------------------------------------------------------------------
__global__ __launch_bounds__(256) void ghist_kernel(const float* __restrict__ x,
                                                    unsigned* __restrict__ gpart) {
    __shared__ unsigned lh[4 * NB];  // 4 KB
    const int tid = threadIdx.x;
    lh[tid] = 0u; lh[NB + tid] = 0u; lh[2 * NB + tid] = 0u; lh[3 * NB + tid] = 0u;
    __syncthreads();

    const float4* __restrict__ xb =
        (const float4*)x + (size_t)blockIdx.x * F4_PER_BLOCK;
    float4 v[8];
#pragma unroll
    for (int it = 0; it < 8; ++it) v[it] = xb[it * 256 + tid];

    unsigned* wl = lh + ((tid >> 6) << 8);  // this wave's private hist
#pragma unroll
    for (int it = 0; it < 8; ++it) {
        const float vv[4] = {v[it].x, v[it].y, v[it].z, v[it].w};
#pragma unroll
        for (int e = 0; e < 4; ++e) {
            const float f = vv[e];
            if (f >= 0.f && f <= 1.f) {      // histc: OOR dropped
                int bin = (int)(f * 256.f);  // floor (f>=0)
                if (bin > 255) bin = 255;    // v==1 -> last bin
                atomicAdd(&wl[bin], 1u);
            }
        }
    }
    __syncthreads();
    const unsigned s = lh[tid] + lh[NB + tid] + lh[2 * NB + tid] + lh[3 * NB + tid];
    if (s) atomicAdd(&gpart[((blockIdx.x & (NPART - 1)) << 8) + tid], s);
}

// ---------------------------------------------------------------------------
// Kernel 2: row-0 per-column histograms (u16-packed). Reads ONLY the row-0
// strips: 8192 planes x 224 B = 1.75 MB. Block = 32 planes (448 float4).
// Packing safety: per-(w,bin) per block <= 32; global <= 8192 < 2^16.
// ---------------------------------------------------------------------------
__global__ __launch_bounds__(256) void colhist_kernel(const float* __restrict__ x,
                                                      unsigned* __restrict__ colhist) {
    __shared__ unsigned ch[HH * NWORD];  // 28 KB
    const int tid = threadIdx.x;
    for (int i = tid; i < HH * NWORD; i += 256) ch[i] = 0u;
    __syncthreads();

    const float* __restrict__ xb = x + (size_t)blockIdx.x * 32 * PLANE;
    for (int j = tid; j < 32 * 14; j += 256) {  // 448 float4 of row-0 data
        const int pl = j / 14;
        const int wq = j - pl * 14;
        const float4 v = *(const float4*)(xb + (size_t)pl * PLANE + wq * 4);
        const float vv[4] = {v.x, v.y, v.z, v.w};
#pragma unroll
        for (int e = 0; e < 4; ++e) {
            const float f = vv[e];
            if (f >= 0.f && f <= 1.f) {
                int bin = (int)(f * 256.f);
                if (bin > 255) bin = 255;
                atomicAdd(&ch[(wq * 4 + e) * NWORD + (bin >> 1)],
                          1u << ((bin & 1) << 4));
            }
        }
    }
    __syncthreads();
    for (int i = tid; i < HH * NWORD; i += 256) {
        const unsigned v = ch[i];
        if (v) atomicAdd(&colhist[i], v);
    }
}

// ---------------------------------------------------------------------------
// Wave / entropy helpers (identical reduction order to the proven kernel).
// ---------------------------------------------------------------------------
__device__ __forceinline__ float wave_sum(float v) {
#pragma unroll
    for (int off = 32; off > 0; off >>= 1) v += __shfl_xor(v, off);
    return v;
}

__device__ __forceinline__ float ilook(const unsigned* __restrict__ integ,
                                       int a, int b, int bin) {
    return (a == 0 || b == 0)
               ? 0.f
               : (float)integ[((size_t)((a - 1) * WW + (b - 1))) * NB + bin];
}

__device__ float region_ent(const unsigned* __restrict__ integ, int lane,
                            int xd, int ys, int yd) {
    float hb[4];
    float hs = 0.f;
#pragma unroll
    for (int k = 0; k < 4; k++) {
        const int bin = lane + 64 * k;
        const float hv = ilook(integ, xd, yd, bin) - ilook(integ, xd, ys, bin);
        hb[k] = hv;
        hs += hv;
    }
    hs = wave_sum(hs);
    float e = 0.f;
#pragma unroll
    for (int k = 0; k < 4; k++) {
        const float p = hb[k] / hs;
        e += p * log2f(p + 1e-9f);
    }
    return -wave_sum(e);
}

// ---------------------------------------------------------------------------
// Kernel 3: fast decide. ent_y from colhist, argmax -> ys0; total_ent from
// the 16 gpart partials; Ts0 = ent_y[ys0]/total_ent. flag=1 done, flag=2 cont.
// ---------------------------------------------------------------------------
__global__ __launch_bounds__(1024) void decide_fast_kernel(
    const unsigned* __restrict__ colhist, const unsigned* __restrict__ gpart,
    int* __restrict__ region, unsigned* __restrict__ flag) {
    __shared__ float ent_s[WW];
    const int tid = threadIdx.x;
    const int lane = tid & 63;
    const int wv = tid >> 6;

    for (int w = wv; w < WW; w += 16) {
        float hb[4], hs = 0.f;
#pragma unroll
        for (int k = 0; k < 4; k++) {
            const int bin = lane + 64 * k;
            const unsigned wd = colhist[w * NWORD + (bin >> 1)];
            hb[k] = (float)((wd >> ((bin & 1) << 4)) & 0xffffu);
            hs += hb[k];
        }
        hs = wave_sum(hs);
        float e = 0.f;
#pragma unroll
        for (int k = 0; k < 4; k++) {
            const float p = hb[k] / hs;
            e += p * log2f(p + 1e-9f);
        }
        e = -wave_sum(e);
        if (lane == 0) ent_s[w] = e;
    }
    __syncthreads();
    if (wv != 0) return;

    float best = -3.0e38f;
    int bestw = 0;
    for (int w = 0; w < WW; ++w) {
        const float e = ent_s[w];
        if (e > best) { best = e; bestw = w; }  // strict > keeps FIRST max
    }

    // total entropy from the 16 partial global histograms
    float hb[4], hs = 0.f;
#pragma unroll
    for (int k = 0; k < 4; k++) {
        const int bin = lane + 64 * k;
        unsigned t = 0;
#pragma unroll
        for (int p = 0; p < NPART; ++p) t += gpart[(p << 8) + bin];
        hb[k] = (float)t;
        hs += hb[k];
    }
    hs = wave_sum(hs);
    float e = 0.f;
#pragma unroll
    for (int k = 0; k < 4; k++) {
        const float p = hb[k] / hs;
        e += p * log2f(p + 1e-9f);
    }
    const float total_ent = -wave_sum(e);

    const float Ts0 = best / total_ent;
    if (lane == 0) {
        region[0] = 1;          // xd
        region[1] = bestw;      // ys
        region[2] = bestw + 1;  // yd
        *flag = (Ts0 >= 0.9f) ? 1u : 2u;
    }
}

// ---------------------------------------------------------------------------
// Kernel 4: cooperative fallback — full integral-histogram pipeline, only if
// the greedy loop actually needs to iterate (flag==2). Fast path: every block
// reads flag and returns.
// ---------------------------------------------------------------------------
__global__ __launch_bounds__(256) void fallback_kernel(
    const float* __restrict__ x, unsigned* __restrict__ ps,
    unsigned* __restrict__ hist, int* __restrict__ region,
    const unsigned* __restrict__ flag) {
    if (*flag == 1u) return;  // all blocks exit together; no sync reached
    cg::grid_group grid = cg::this_grid();
    __shared__ unsigned lh[HH * NWORD];  // 7168 words, u16-packed
    const int tid = threadIdx.x;
    const int gtid = blockIdx.x * 256 + tid;

    // phase 1: per-(h,slice) tile histograms -> ps (non-atomic, tile-owned)
    for (int t = blockIdx.x; t < HH * SLICES; t += 256) {
        const int h = t % HH;
        const int slice = t / HH;
        for (int i = tid; i < HH * NWORD; i += 256) lh[i] = 0u;
        __syncthreads();
        const float* __restrict__ xb =
            x + (size_t)(slice * PL_PER_SLICE) * PLANE + h * WW;
        for (int it = 0; it < 28; ++it) {  // 512 planes * 14 float4 / 256
            const int j = it * 256 + tid;
            const int bcl = j / 14;
            const int wq = j - bcl * 14;
            const float4 v = *(const float4*)(xb + (size_t)bcl * PLANE + wq * 4);
            const float vv[4] = {v.x, v.y, v.z, v.w};
#pragma unroll
            for (int e = 0; e < 4; ++e) {
                const float f = vv[e];
                if (f >= 0.f && f <= 1.f) {
                    int bin = (int)(f * 256.f);
                    if (bin > 255) bin = 255;
                    atomicAdd(&lh[(wq * 4 + e) * NWORD + (bin >> 1)],
                              1u << ((bin & 1) << 4));
                }
            }
        }
        __syncthreads();
        unsigned* g = ps + (size_t)slice * CELLW + (size_t)h * WW * NWORD;
        for (int i = tid; i < HH * NWORD; i += 256) g[i] = lh[i];
        __syncthreads();
    }
    grid.sync();

    // phase 2: reduce 16 slices + unpack -> hist u32 [h][w][256]
    for (int idx = gtid; idx < CELLW; idx += 256 * 256) {
        unsigned s = 0;
#pragma unroll
        for (int sl = 0; sl < SLICES; ++sl) s += ps[(size_t)sl * CELLW + idx];
        ((uint2*)hist)[idx] = make_uint2(s & 0xffffu, s >> 16);
    }
    grid.sync();

    // phase 3: inclusive prefix along w (register-staged)
    if (gtid < HH * NB) {
        const int h = gtid >> 8, b = gtid & 255;
        unsigned* base = hist + (size_t)h * WW * NB + b;
        unsigned v[WW];
#pragma unroll
        for (int w = 0; w < WW; ++w) v[w] = base[(size_t)w * NB];
        unsigned c = 0;
#pragma unroll
        for (int w = 0; w < WW; ++w) { c += v[w]; base[(size_t)w * NB] = c; }
    }
    grid.sync();

    // phase 4: inclusive prefix along h
    if (gtid < WW * NB) {
        const int w = gtid >> 8, b = gtid & 255;
        unsigned* base = hist + (size_t)w * NB + b;
        unsigned v[HH];
#pragma unroll
        for (int h = 0; h < HH; ++h) v[h] = base[(size_t)h * WW * NB];
        unsigned c = 0;
#pragma unroll
        for (int h = 0; h < HH; ++h) { c += v[h]; base[(size_t)h * WW * NB] = c; }
    }
    grid.sync();

    // phase 5: greedy loop, block 0 wave 0, starting from fast-path region
    if (blockIdx.x == 0 && tid < 64) {
        const int lane = tid;
        const float total_ent = region_ent(hist, lane, HH, 0, WW);
        int xd = region[0], ys = region[1], yd = region[2];
        float Ts = region_ent(hist, lane, xd, ys, yd) / total_ent;
        bool done = false;
        int iter = 0;
        while (Ts < 0.9f && !done && iter < 1000) {
            iter++;
            const float e_cur = region_ent(hist, lane, xd, ys, yd);
            const int ysm = (ys - 1 < 0) ? 0 : ys - 1;
            const int ydp = (yd + 1 > WW) ? WW : yd + 1;
            const bool c1 = (xd + 1 < HH) &&
                            (region_ent(hist, lane, xd + 1, ys, yd) > e_cur);
            const bool c2 = !c1 && (ys - 1 >= 0) &&
                            (region_ent(hist, lane, xd, ysm, yd) > e_cur);
            const bool c3 = !c1 && !c2 && (yd + 1 < WW) &&
                            (region_ent(hist, lane, xd, ys, ydp) > e_cur);
            if (c1) xd = xd + 1;
            else if (c2) ys = ys - 1;
            else if (c3) yd = yd + 1;
            done = !(c1 || c2 || c3);
            Ts = region_ent(hist, lane, xd, ys, yd) / total_ent;
        }
        if (lane == 0) {
            region[0] = xd;
            region[1] = ys;
            region[2] = yd;
        }
    }
}

// ---------------------------------------------------------------------------
// Kernel 5: masked mean-pool. 32 blocks x 256. Small region (fast path):
// thread-per-plane. Large: wave-per-plane with lane striding.
// ---------------------------------------------------------------------------
__global__ __launch_bounds__(256) void pool_kernel(const float* __restrict__ x,
                                                   const int* __restrict__ region,
                                                   float* __restrict__ pooled) {
    const int xd = region[0], ys = region[1], yd = region[2];
    const int Wd = yd - ys;
    const int n = xd * Wd;
    const float area = fmaxf((float)n, 1.f);
    if (n <= 16) {
        const int bc = blockIdx.x * 256 + threadIdx.x;  // grid 32*256 == BC
        const float* plane = x + (size_t)bc * PLANE;
        float s = 0.f;
        for (int j = 0; j < n; ++j) {
            const int r = j / Wd;
            const int cc = ys + (j - r * Wd);
            s += plane[r * WW + cc];
        }
        pooled[bc] = s / area;
    } else {
        const int wid = (blockIdx.x * 256 + threadIdx.x) >> 6;  // 128 waves
        const int lane = threadIdx.x & 63;
        for (int bc = wid; bc < BC; bc += 128) {
            const float* plane = x + (size_t)bc * PLANE;
            float s = 0.f;
            for (int j = lane; j < n; j += 64) {
                const int r = j / Wd;
                const int cc = ys + (j - r * Wd);
                s += plane[r * WW + cc];
            }
#pragma unroll
            for (int off = 32; off > 0; off >>= 1) s += __shfl_xor(s, off);
            if (lane == 0) pooled[bc] = s / area;
        }
    }
}

// ---------------------------------------------------------------------------
// Kernel 6: FC. Unchanged from the verified kernel (absmax == 0).
// ---------------------------------------------------------------------------
__global__ __launch_bounds__(256) void fc_kernel(const float* __restrict__ pooled,
                                                 const float* __restrict__ wfc,
                                                 float* __restrict__ out) {
    __shared__ float red[240];
    const int b = blockIdx.x;
    const int t = threadIdx.x;
    if (t < 240) {
        const int chunk = t / NCLS;
        const int n = t - chunk * NCLS;
        const float* pv = pooled + b * CC + chunk * 128;
        const float* wv = wfc + (size_t)(chunk * 128) * NCLS + n;
        float a0 = 0.f, a1 = 0.f, a2 = 0.f, a3 = 0.f;
        for (int c = 0; c < 128; c += 4) {
            a0 += pv[c + 0] * wv[(c + 0) * NCLS];
            a1 += pv[c + 1] * wv[(c + 1) * NCLS];
            a2 += pv[c + 2] * wv[(c + 2) * NCLS];
            a3 += pv[c + 3] * wv[(c + 3) * NCLS];
        }
        red[t] = (a0 + a1) + (a2 + a3);
    }
    __syncthreads();
    if (t < NCLS) {
        float s = 0.f;
#pragma unroll
        for (int ch = 0; ch < 8; ++ch) s += red[ch * NCLS + t];
        out[b * NCLS + t] = s;
    }
}

// ---------------------------------------------------------------------------
extern "C" void kernel_launch(void* const* d_in, const int* in_sizes, int n_in,
                              void* d_out, int out_size, void* d_ws, size_t ws_size,
                              hipStream_t stream) {
    const float* x = (const float*)d_in[0];    // [8,1024,56,56]
    const float* wfc = (const float*)d_in[1];  // [1024,30]
    float* out = (float*)d_out;                // [8,30]

    unsigned char* ws = (unsigned char*)d_ws;
    const bool full = (ws_size >= FULL_NEED);

    // fast-path stats alias the head of the fallback's ps buffer (dead by the
    // time fallback overwrites it): colhist 28,672 B then gpart 16,384 B.
    unsigned* colhist = (unsigned*)ws;
    unsigned* gpart = (unsigned*)(ws + HH * NWORD * 4);        // @28,672
    unsigned* ps = (unsigned*)ws;                              // fallback
    unsigned* hist = (unsigned*)(ws + (size_t)SLICES * CELLW * 4);
    int* region;
    unsigned* flag;
    float* pooled;
    if (full) {
        unsigned char* meta = ws + 28901376ull;
        region = (int*)meta;
        flag = (unsigned*)(meta + 16);
        pooled = (float*)(ws + 28901632ull);
    } else {  // tiny-ws fallback: fast path only (stats end @45,056)
        region = (int*)(ws + 46080);
        flag = (unsigned*)(ws + 46080 + 16);
        pooled = (float*)(ws + 47104);
    }

    zero_kernel<<<44, 256, 0, stream>>>(colhist);  // colhist+gpart contiguous
    ghist_kernel<<<GH_BLOCKS, 256, 0, stream>>>(x, gpart);
    colhist_kernel<<<256, 256, 0, stream>>>(x, colhist);
    decide_fast_kernel<<<1, 1024, 0, stream>>>(colhist, gpart, region, flag);
    if (full) {
        const float* xx = x;
        unsigned* psp = ps;
        unsigned* hp = hist;
        int* rp = region;
        unsigned* fp = flag;
        void* kargs[] = {(void*)&xx, (void*)&psp, (void*)&hp, (void*)&rp,
                         (void*)&fp};
        hipLaunchCooperativeKernel((const void*)fallback_kernel, dim3(256),
                                   dim3(256), kargs, 0, stream);
    }
    pool_kernel<<<32, 256, 0, stream>>>(x, region, pooled);
    fc_kernel<<<BB, 256, 0, stream>>>(pooled, wfc, out);
}

// Round 3
// 169.775 us; speedup vs baseline: 1.2720x; 1.1943x over previous
//
#include <hip/hip_runtime.h>
#include <math.h>

#define BB 8
#define CC 1024
#define HH 56
#define WW 56
#define NB 256
#define NCLS 30
#define BC (BB * CC)             // 8192 planes
#define PLANE (HH * WW)          // 3136
#define NWORD (NB / 2)           // 128 packed u16-pairs per cell (fallback)
#define CELLW (PLANE * NWORD)    // 401408 packed words, whole image
#define SLICES 16
#define PL_PER_SLICE (BC / SLICES)  // 512 planes

#define NPART 16                 // partial global hists (atomic-contention split)
#define GH_BLOCKS 3136           // 6,422,528 float4 / 2048 per block
#define F4_PER_BLOCK 2048        // 8 float4 per thread, register-prefetched
#define FB_BLOCKS 256            // fallback grid (1 block/CU -> co-resident)

// ---------------------------------------------------------------------------
// Workspace layout (FULL mode):
//   ps       @ 0          25,690,112 B  (fallback per-slice packed hists)
//   colhist  @ 0              57,344 B  (u32[56][256]; ALIASES ps head — dead
//   gpart    @ 57,344         16,384 B   before fallback overwrites ps)
//   hist     @ 25,690,112  3,211,264 B  (fallback integral hists)
//   meta     @ 28,901,376        64 B  (region int[3] @+0, flag @+16, bar[8] @+32)
// ---------------------------------------------------------------------------
#define FULL_NEED 28934400ull
#define META_OFF 28901376ull

// ---------------------------------------------------------------------------
// Kernel 0: zero colhist + gpart (18,432 u32 contiguous) + barrier counters.
// ---------------------------------------------------------------------------
__global__ void zero_kernel(unsigned* __restrict__ p, unsigned* __restrict__ bar) {
    p[blockIdx.x * 256 + threadIdx.x] = 0u;  // grid 72*256 = 18432 exact
    if (blockIdx.x == 0 && threadIdx.x < 8) bar[threadIdx.x] = 0u;
}

// ---------------------------------------------------------------------------
// Kernel 1: fused global 256-bin histogram + row-0 per-column histograms.
//  grid 3136 x 256, 4 KB LDS, ~7-8 blocks/CU resident.
//  - per-wave privatized LDS hist (4 copies) -> intra-wave contention only
//  - all 8 float4 loads register-prefetched (8 outstanding/thread)
//  - row-0 float4s (li < 56, whole-quad uniform since li%4==0) additionally
//    do one global u32 atomic into colhist[col*256+bin] (57 KB, L2-resident;
//    458,752 atomics total ~= 2% of elements)
//  - flush into gpart[blockIdx&15] -> same-address chains 196 deep not 3136
// ---------------------------------------------------------------------------
__global__ __launch_bounds__(256) void ghist_kernel(const float* __restrict__ x,
                                                    unsigned* __restrict__ colhist,
                                                    unsigned* __restrict__ gpart) {
    __shared__ unsigned lh[4 * NB];  // 4 KB
    const int tid = threadIdx.x;
    lh[tid] = 0u; lh[NB + tid] = 0u; lh[2 * NB + tid] = 0u; lh[3 * NB + tid] = 0u;
    __syncthreads();

    const size_t base_f4 = (size_t)blockIdx.x * F4_PER_BLOCK;
    const float4* __restrict__ xb = (const float4*)x + base_f4;
    float4 v[8];
#pragma unroll
    for (int it = 0; it < 8; ++it) v[it] = xb[it * 256 + tid];

    unsigned* wl = lh + ((tid >> 6) << 8);  // this wave's private hist
#pragma unroll
    for (int it = 0; it < 8; ++it) {
        const int j = it * 256 + tid;
        const int e0 = ((int)base_f4 + j) * 4;   // global element idx (<25.7M)
        const int pl = e0 / PLANE;               // const-div -> magic mul
        const int li = e0 - pl * PLANE;          // plane-local, multiple of 4
        const bool r0 = (li < WW);               // whole float4 is row 0
        const float vv[4] = {v[it].x, v[it].y, v[it].z, v[it].w};
#pragma unroll
        for (int e = 0; e < 4; ++e) {
            const float f = vv[e];
            if (f >= 0.f && f <= 1.f) {          // histc: OOR dropped
                int bin = (int)(f * 256.f);      // floor (f>=0)
                if (bin > 255) bin = 255;        // v==1 -> last bin
                atomicAdd(&wl[bin], 1u);
                if (r0) atomicAdd(&colhist[(li + e) * NB + bin], 1u);
            }
        }
    }
    __syncthreads();
    const unsigned s = lh[tid] + lh[NB + tid] + lh[2 * NB + tid] + lh[3 * NB + tid];
    if (s) atomicAdd(&gpart[((blockIdx.x & (NPART - 1)) << 8) + tid], s);
}

// ---------------------------------------------------------------------------
// Wave / entropy helpers (identical reduction order to the verified kernel).
// ---------------------------------------------------------------------------
__device__ __forceinline__ float wave_sum(float v) {
#pragma unroll
    for (int off = 32; off > 0; off >>= 1) v += __shfl_xor(v, off);
    return v;
}

__device__ __forceinline__ float ilook(const unsigned* __restrict__ integ,
                                       int a, int b, int bin) {
    return (a == 0 || b == 0)
               ? 0.f
               : (float)integ[((size_t)((a - 1) * WW + (b - 1))) * NB + bin];
}

__device__ float region_ent(const unsigned* __restrict__ integ, int lane,
                            int xd, int ys, int yd) {
    float hb[4];
    float hs = 0.f;
#pragma unroll
    for (int k = 0; k < 4; k++) {
        const int bin = lane + 64 * k;
        const float hv = ilook(integ, xd, yd, bin) - ilook(integ, xd, ys, bin);
        hb[k] = hv;
        hs += hv;
    }
    hs = wave_sum(hs);
    float e = 0.f;
#pragma unroll
    for (int k = 0; k < 4; k++) {
        const float p = hb[k] / hs;
        e += p * log2f(p + 1e-9f);
    }
    return -wave_sum(e);
}

// ---------------------------------------------------------------------------
// Kernel 2: fast decide. ent_y from colhist (u32), argmax -> ys0; total_ent
// from the 16 gpart partials; Ts0 = ent_y[ys0]/total_ent (single-cell region
// entropy == column entropy: identical integer counts). flag=1 done, 2 cont.
// ---------------------------------------------------------------------------
__global__ __launch_bounds__(1024) void decide_fast_kernel(
    const unsigned* __restrict__ colhist, const unsigned* __restrict__ gpart,
    int* __restrict__ region, unsigned* __restrict__ flag) {
    __shared__ float ent_s[WW];
    const int tid = threadIdx.x;
    const int lane = tid & 63;
    const int wv = tid >> 6;

    for (int w = wv; w < WW; w += 16) {
        float hb[4], hs = 0.f;
#pragma unroll
        for (int k = 0; k < 4; k++) {
            const int bin = lane + 64 * k;
            hb[k] = (float)colhist[w * NB + bin];
            hs += hb[k];
        }
        hs = wave_sum(hs);
        float e = 0.f;
#pragma unroll
        for (int k = 0; k < 4; k++) {
            const float p = hb[k] / hs;
            e += p * log2f(p + 1e-9f);
        }
        e = -wave_sum(e);
        if (lane == 0) ent_s[w] = e;
    }
    __syncthreads();
    if (wv != 0) return;

    float best = -3.0e38f;
    int bestw = 0;
    for (int w = 0; w < WW; ++w) {
        const float e = ent_s[w];
        if (e > best) { best = e; bestw = w; }  // strict > keeps FIRST max
    }

    // total entropy from the 16 partial global histograms
    float hb[4], hs = 0.f;
#pragma unroll
    for (int k = 0; k < 4; k++) {
        const int bin = lane + 64 * k;
        unsigned t = 0;
#pragma unroll
        for (int p = 0; p < NPART; ++p) t += gpart[(p << 8) + bin];
        hb[k] = (float)t;
        hs += hb[k];
    }
    hs = wave_sum(hs);
    float e = 0.f;
#pragma unroll
    for (int k = 0; k < 4; k++) {
        const float p = hb[k] / hs;
        e += p * log2f(p + 1e-9f);
    }
    const float total_ent = -wave_sum(e);

    const float Ts0 = best / total_ent;
    if (lane == 0) {
        region[0] = 1;          // xd
        region[1] = bestw;      // ys
        region[2] = bestw + 1;  // yd
        *flag = (Ts0 >= 0.9f) ? 1u : 2u;
    }
}

// ---------------------------------------------------------------------------
// Software grid barrier (fallback path only; never runs on flag==1).
// 256 blocks on 256 CUs, 28 KB LDS, 256 thr -> co-resident on an idle device.
// Device-scope atomics + threadfence for cross-XCD visibility.
// ---------------------------------------------------------------------------
__device__ __forceinline__ void soft_grid_sync(unsigned* __restrict__ bar,
                                               int idx, unsigned nb) {
    __syncthreads();
    if (threadIdx.x == 0) {
        __threadfence();                       // release: my writes visible
        atomicAdd(&bar[idx], 1u);
        while (atomicAdd(&bar[idx], 0u) < nb) {
            __builtin_amdgcn_s_sleep(8);
        }
    }
    __syncthreads();
    __threadfence();                           // acquire: see others' writes
}

// ---------------------------------------------------------------------------
// Kernel 3: fallback — full integral-histogram pipeline, ordinary launch,
// gated on flag==2 (bench data: flag==1, every block exits immediately).
// ---------------------------------------------------------------------------
__global__ __launch_bounds__(256) void fallback_kernel(
    const float* __restrict__ x, unsigned* __restrict__ ps,
    unsigned* __restrict__ hist, int* __restrict__ region,
    const unsigned* __restrict__ flag, unsigned* __restrict__ bar) {
    if (*flag == 1u) return;  // all blocks exit together; no barrier reached
    __shared__ unsigned lh[HH * NWORD];  // 7168 words, u16-packed (28 KB)
    const int tid = threadIdx.x;
    const int gtid = blockIdx.x * 256 + tid;

    // phase 1: per-(h,slice) tile histograms -> ps (non-atomic, tile-owned)
    for (int t = blockIdx.x; t < HH * SLICES; t += FB_BLOCKS) {
        const int h = t % HH;
        const int slice = t / HH;
        for (int i = tid; i < HH * NWORD; i += 256) lh[i] = 0u;
        __syncthreads();
        const float* __restrict__ xb =
            x + (size_t)(slice * PL_PER_SLICE) * PLANE + h * WW;
        for (int it = 0; it < 28; ++it) {  // 512 planes * 14 float4 / 256
            const int j = it * 256 + tid;
            const int bcl = j / 14;
            const int wq = j - bcl * 14;
            const float4 v = *(const float4*)(xb + (size_t)bcl * PLANE + wq * 4);
            const float vv[4] = {v.x, v.y, v.z, v.w};
#pragma unroll
            for (int e = 0; e < 4; ++e) {
                const float f = vv[e];
                if (f >= 0.f && f <= 1.f) {
                    int bin = (int)(f * 256.f);
                    if (bin > 255) bin = 255;
                    atomicAdd(&lh[(wq * 4 + e) * NWORD + (bin >> 1)],
                              1u << ((bin & 1) << 4));
                }
            }
        }
        __syncthreads();
        unsigned* g = ps + (size_t)slice * CELLW + (size_t)h * WW * NWORD;
        for (int i = tid; i < HH * NWORD; i += 256) g[i] = lh[i];
        __syncthreads();
    }
    soft_grid_sync(bar, 0, FB_BLOCKS);

    // phase 2: reduce 16 slices + unpack -> hist u32 [h][w][256]
    for (int idx = gtid; idx < CELLW; idx += FB_BLOCKS * 256) {
        unsigned s = 0;
#pragma unroll
        for (int sl = 0; sl < SLICES; ++sl) s += ps[(size_t)sl * CELLW + idx];
        ((uint2*)hist)[idx] = make_uint2(s & 0xffffu, s >> 16);
    }
    soft_grid_sync(bar, 1, FB_BLOCKS);

    // phase 3: inclusive prefix along w (register-staged)
    if (gtid < HH * NB) {
        const int h = gtid >> 8, b = gtid & 255;
        unsigned* base = hist + (size_t)h * WW * NB + b;
        unsigned v[WW];
#pragma unroll
        for (int w = 0; w < WW; ++w) v[w] = base[(size_t)w * NB];
        unsigned c = 0;
#pragma unroll
        for (int w = 0; w < WW; ++w) { c += v[w]; base[(size_t)w * NB] = c; }
    }
    soft_grid_sync(bar, 2, FB_BLOCKS);

    // phase 4: inclusive prefix along h
    if (gtid < WW * NB) {
        const int w = gtid >> 8, b = gtid & 255;
        unsigned* base = hist + (size_t)w * NB + b;
        unsigned v[HH];
#pragma unroll
        for (int h = 0; h < HH; ++h) v[h] = base[(size_t)h * WW * NB];
        unsigned c = 0;
#pragma unroll
        for (int h = 0; h < HH; ++h) { c += v[h]; base[(size_t)h * WW * NB] = c; }
    }
    soft_grid_sync(bar, 3, FB_BLOCKS);

    // phase 5: greedy loop, block 0 wave 0, starting from fast-path region
    if (blockIdx.x == 0 && tid < 64) {
        const int lane = tid;
        const float total_ent = region_ent(hist, lane, HH, 0, WW);
        int xd = region[0], ys = region[1], yd = region[2];
        float Ts = region_ent(hist, lane, xd, ys, yd) / total_ent;
        bool done = false;
        int iter = 0;
        while (Ts < 0.9f && !done && iter < 1000) {
            iter++;
            const float e_cur = region_ent(hist, lane, xd, ys, yd);
            const int ysm = (ys - 1 < 0) ? 0 : ys - 1;
            const int ydp = (yd + 1 > WW) ? WW : yd + 1;
            const bool c1 = (xd + 1 < HH) &&
                            (region_ent(hist, lane, xd + 1, ys, yd) > e_cur);
            const bool c2 = !c1 && (ys - 1 >= 0) &&
                            (region_ent(hist, lane, xd, ysm, yd) > e_cur);
            const bool c3 = !c1 && !c2 && (yd + 1 < WW) &&
                            (region_ent(hist, lane, xd, ys, ydp) > e_cur);
            if (c1) xd = xd + 1;
            else if (c2) ys = ys - 1;
            else if (c3) yd = yd + 1;
            done = !(c1 || c2 || c3);
            Ts = region_ent(hist, lane, xd, ys, yd) / total_ent;
        }
        if (lane == 0) {
            region[0] = xd;
            region[1] = ys;
            region[2] = yd;
        }
    }
}

// ---------------------------------------------------------------------------
// Kernel 4: fused pool + FC. Block = batch b. Phase A: 256 threads gather
// pooled[1024] into LDS (fast path n==1: one pixel per plane). Phase B: the
// verified 8-chunk x 30-class GEMV with LDS reduce.
// ---------------------------------------------------------------------------
__global__ __launch_bounds__(256) void fc_kernel(const float* __restrict__ x,
                                                 const int* __restrict__ region,
                                                 const float* __restrict__ wfc,
                                                 float* __restrict__ out) {
    __shared__ float pl_s[CC];   // 4 KB pooled for this b
    __shared__ float red[240];
    const int b = blockIdx.x;
    const int t = threadIdx.x;
    const int xd = region[0], ys = region[1], yd = region[2];
    const int Wd = yd - ys;
    const int n = xd * Wd;
    const float area = fmaxf((float)n, 1.f);
    const float* __restrict__ xb = x + (size_t)b * CC * PLANE;
#pragma unroll
    for (int k = 0; k < 4; ++k) {
        const int c = t + k * 256;
        const float* plane = xb + (size_t)c * PLANE;
        float s = 0.f;
        for (int j = 0; j < n; ++j) {
            const int r = j / Wd;
            const int cc2 = ys + (j - r * Wd);
            s += plane[r * WW + cc2];
        }
        pl_s[c] = s / area;
    }
    __syncthreads();
    if (t < 240) {
        const int chunk = t / NCLS;
        const int nn = t - chunk * NCLS;
        const float* pv = pl_s + chunk * 128;
        const float* wv = wfc + (size_t)(chunk * 128) * NCLS + nn;
        float a0 = 0.f, a1 = 0.f, a2 = 0.f, a3 = 0.f;
        for (int c = 0; c < 128; c += 4) {
            a0 += pv[c + 0] * wv[(c + 0) * NCLS];
            a1 += pv[c + 1] * wv[(c + 1) * NCLS];
            a2 += pv[c + 2] * wv[(c + 2) * NCLS];
            a3 += pv[c + 3] * wv[(c + 3) * NCLS];
        }
        red[t] = (a0 + a1) + (a2 + a3);
    }
    __syncthreads();
    if (t < NCLS) {
        float s = 0.f;
#pragma unroll
        for (int ch = 0; ch < 8; ++ch) s += red[ch * NCLS + t];
        out[b * NCLS + t] = s;
    }
}

// ---------------------------------------------------------------------------
extern "C" void kernel_launch(void* const* d_in, const int* in_sizes, int n_in,
                              void* d_out, int out_size, void* d_ws, size_t ws_size,
                              hipStream_t stream) {
    const float* x = (const float*)d_in[0];    // [8,1024,56,56]
    const float* wfc = (const float*)d_in[1];  // [1024,30]
    float* out = (float*)d_out;                // [8,30]

    unsigned char* ws = (unsigned char*)d_ws;
    const bool full = (ws_size >= FULL_NEED);

    // fast-path stats alias the head of the fallback's ps buffer (dead before
    // fallback overwrites): colhist u32 57,344 B then gpart 16,384 B.
    unsigned* colhist = (unsigned*)ws;
    unsigned* gpart = (unsigned*)(ws + 57344);
    unsigned* ps = (unsigned*)ws;                                   // fallback
    unsigned* hist = (unsigned*)(ws + (size_t)SLICES * CELLW * 4);  // fallback
    int* region;
    unsigned* flag;
    unsigned* bar;
    if (full) {
        unsigned char* meta = ws + META_OFF;  // outside ps+hist
        region = (int*)meta;
        flag = (unsigned*)(meta + 16);
        bar = (unsigned*)(meta + 32);
    } else {  // tiny-ws: fast path only (stats end @73,728)
        region = (int*)(ws + 73728);
        flag = (unsigned*)(ws + 73728 + 16);
        bar = (unsigned*)(ws + 73728 + 32);
    }

    zero_kernel<<<72, 256, 0, stream>>>(colhist, bar);  // colhist+gpart contig
    ghist_kernel<<<GH_BLOCKS, 256, 0, stream>>>(x, colhist, gpart);
    decide_fast_kernel<<<1, 1024, 0, stream>>>(colhist, gpart, region, flag);
    if (full) {
        fallback_kernel<<<FB_BLOCKS, 256, 0, stream>>>(x, ps, hist, region,
                                                       flag, bar);
    }
    fc_kernel<<<BB, 256, 0, stream>>>(x, region, wfc, out);
}